// Round 8
// baseline (263.433 us; speedup 1.0000x reference)
//
#include <hip/hip_runtime.h>
#include <hip/hip_bf16.h>

#define NB 256
#define DD 65536
#define NN 41
#define GG 2048
#define OO 256
#define NO 10496
#define EE 512
#define NEG_SLOPE 0.2f

typedef __attribute__((ext_vector_type(8))) short bf16x8;
typedef __attribute__((ext_vector_type(4))) float f32x4;
typedef unsigned int u32;

// async global->LDS, 16B per lane (used by gemm2 only now).
__device__ __forceinline__ void gl_lds16(const __hip_bfloat16* gsrc, __hip_bfloat16* lds) {
    __builtin_amdgcn_global_load_lds((const __attribute__((address_space(1))) u32*)gsrc,
                                     (__attribute__((address_space(3))) u32*)lds, 16, 0, 0);
}

__device__ __forceinline__ u32 pack_bf2(float lo, float hi) {
    u32 a = (u32)__bfloat16_as_ushort(__float2bfloat16(lo));
    u32 b = (u32)__bfloat16_as_ushort(__float2bfloat16(hi));
    return a | (b << 16);
}

// ---- fallback transpose for W3 (standalone) ----
__global__ __launch_bounds__(256) void transpose_w3_k(const float* __restrict__ W3,
                                                      __hip_bfloat16* __restrict__ W3t) {
    __shared__ u32 tb[64 * 128];
    int rem = blockIdx.x;
    int kc0 = (rem >> 3) * 256;
    int o0 = (rem & 7) * 64;
    int t = threadIdx.x;
    int p = t & 127;
    int oh = (t >> 7) * 32;
    const float* r0 = W3 + (size_t)(kc0 + 2 * p) * EE + o0 + oh;
    const float* r1 = r0 + EE;
#pragma unroll
    for (int c = 0; c < 8; ++c) {
        float4 a = *(const float4*)&r0[c * 4];
        float4 b = *(const float4*)&r1[c * 4];
        tb[(oh + c * 4 + 0) * 128 + p] = pack_bf2(a.x, b.x);
        tb[(oh + c * 4 + 1) * 128 + p] = pack_bf2(a.y, b.y);
        tb[(oh + c * 4 + 2) * 128 + p] = pack_bf2(a.z, b.z);
        tb[(oh + c * 4 + 3) * 128 + p] = pack_bf2(a.w, b.w);
    }
    __syncthreads();
    int w = t >> 6, l = t & 63;
    int lr = l >> 5;
    int ls = l & 31;
#pragma unroll
    for (int j = 0; j < 8; ++j) {
        int o = j * 8 + w * 2 + lr;
        uint4 v = *(const uint4*)&tb[o * 128 + ls * 4];
        *(uint4*)&W3t[(size_t)(o0 + o) * NO + kc0 + ls * 8] = v;
    }
}

// ---- merged prep: gather (blocks 0..255) + W3 transpose (blocks 256..583) ----
// saves the serial W3 pass + a launch bubble. 1024 thr, 128 KiB dynamic LDS.
__global__ __launch_bounds__(1024) void prep_k(const float* __restrict__ x,
                                               const int* __restrict__ idx,
                                               const float* __restrict__ W3,
                                               __hip_bfloat16* __restrict__ g,
                                               __hip_bfloat16* __restrict__ W3t) {
    extern __shared__ __hip_bfloat16 xr[];  // 131072 bytes
    int t = threadIdx.x;
    if (blockIdx.x < NB) {
        int b = blockIdx.x;
        const float4* xv = (const float4*)(x + (size_t)b * DD);
#pragma unroll
        for (int i = 0; i < 16; ++i) {
            float4 v = xv[t + 1024 * i];
            short4 p;
            p.x = (short)__bfloat16_as_ushort(__float2bfloat16(v.x));
            p.y = (short)__bfloat16_as_ushort(__float2bfloat16(v.y));
            p.z = (short)__bfloat16_as_ushort(__float2bfloat16(v.z));
            p.w = (short)__bfloat16_as_ushort(__float2bfloat16(v.w));
            *(short4*)&xr[(t + 1024 * i) * 4] = p;
        }
        __syncthreads();
        const int4* idx4 = (const int4*)idx;
        for (int u = t; u < NN * GG / 4; u += 1024) {
            int4 ii = idx4[u];
            int n = u >> 9;
            int k = (u & 511) * 4;
            ushort4 o;
            o.x = __bfloat16_as_ushort(xr[ii.x]);
            o.y = __bfloat16_as_ushort(xr[ii.y]);
            o.z = __bfloat16_as_ushort(xr[ii.z]);
            o.w = __bfloat16_as_ushort(xr[ii.w]);
            *(ushort4*)&g[((size_t)n * NB + b) * GG + k] = o;
        }
    } else {
        int c = blockIdx.x - NB;          // 0..327
        int kc0 = (c >> 3) * 256;
        int o0 = (c & 7) * 64;
        u32* tb = (u32*)xr;               // [64 o][128 kpair]
        int p = t & 127;                  // k-pair
        int oh = (t >> 7) * 8;            // 8 o-cols per 128-thr group
        const float* r0 = W3 + (size_t)(kc0 + 2 * p) * EE + o0 + oh;
        const float* r1 = r0 + EE;
#pragma unroll
        for (int cc = 0; cc < 2; ++cc) {
            float4 a = *(const float4*)&r0[cc * 4];
            float4 b = *(const float4*)&r1[cc * 4];
            tb[(oh + cc * 4 + 0) * 128 + p] = pack_bf2(a.x, b.x);
            tb[(oh + cc * 4 + 1) * 128 + p] = pack_bf2(a.y, b.y);
            tb[(oh + cc * 4 + 2) * 128 + p] = pack_bf2(a.z, b.z);
            tb[(oh + cc * 4 + 3) * 128 + p] = pack_bf2(a.w, b.w);
        }
        __syncthreads();
        int o = t >> 4;                   // 0..63
        int ls = t & 15;                  // 16B segment (x2)
        uint4 v0 = *(const uint4*)&tb[o * 128 + ls * 4];
        uint4 v1 = *(const uint4*)&tb[o * 128 + (ls + 16) * 4];
        __hip_bfloat16* drow = &W3t[(size_t)(o0 + o) * NO + kc0];
        *(uint4*)&drow[ls * 8] = v0;
        *(uint4*)&drow[(ls + 16) * 8] = v1;
    }
}

// ---- fallback gather (half row in 64 KiB static LDS) ----
__global__ __launch_bounds__(512) void gather_half_k(const float* __restrict__ x,
                                                     const int* __restrict__ idx,
                                                     __hip_bfloat16* __restrict__ g) {
    __shared__ __align__(16) __hip_bfloat16 xr[32768];
    int b = blockIdx.x >> 1;
    int h = blockIdx.x & 1;
    int t = threadIdx.x;
    const float4* xv = (const float4*)(x + (size_t)b * DD + h * 32768);
#pragma unroll
    for (int i = 0; i < 16; ++i) {
        float4 v = xv[t + 512 * i];
        short4 p;
        p.x = (short)__bfloat16_as_ushort(__float2bfloat16(v.x));
        p.y = (short)__bfloat16_as_ushort(__float2bfloat16(v.y));
        p.z = (short)__bfloat16_as_ushort(__float2bfloat16(v.z));
        p.w = (short)__bfloat16_as_ushort(__float2bfloat16(v.w));
        *(short4*)&xr[(t + 512 * i) * 4] = p;
    }
    __syncthreads();
    const int4* idx4 = (const int4*)idx;
    for (int u = t; u < NN * GG / 4; u += 512) {
        int4 ii = idx4[u];
        int n = u >> 9;
        int k = (u & 511) * 4;
        __hip_bfloat16* dst = &g[((size_t)n * NB + b) * GG + k];
        if ((ii.x >> 15) == h) dst[0] = xr[ii.x & 32767];
        if ((ii.y >> 15) == h) dst[1] = xr[ii.y & 32767];
        if ((ii.z >> 15) == h) dst[2] = xr[ii.z & 32767];
        if ((ii.w >> 15) == h) dst[3] = xr[ii.w & 32767];
    }
}

// ---- GEMM1: 256m x 128o, split-K=4, 512 thr. T14 reg-staged 2-deep pipeline:
// global loads (A from g, B from W fp32) issued 2 tiles ahead into named X/Y reg
// sets; reg->LDS writes after MFMA. Compiler emits counted vmcnt for the reg
// uses, so the __syncthreads drain finds vmcnt already ~0 — no per-iter
// full-latency stall (the rounds-5..7 invariant 54us). Same LDS layout/math.
__global__ __launch_bounds__(512) void gemm1_k(const __hip_bfloat16* __restrict__ g,
                                               const float* __restrict__ W,
                                               __hip_bfloat16* __restrict__ part1) {
    int bid0 = blockIdx.x;
    int bid = (bid0 & 7) * 41 + (bid0 >> 3);
    int s = bid & 3;
    int o0 = ((bid >> 2) & 1) * 128;
    int n = bid >> 3;
    const __hip_bfloat16* srcA = g + (size_t)n * NB * GG + s * 512;
    const float* srcB = W + ((size_t)n * GG + s * 512) * OO + o0;
    __shared__ __align__(16) __hip_bfloat16 lA[2][256 * 32];  // 32 KiB
    __shared__ __align__(16) u32 lB[2][128 * 16];             // 16 KiB
    int t = threadIdx.x;
    int lane = t & 63, w = t >> 6;
    int mw = (w >> 1) * 64, ow = (w & 1) * 64;
    int lrow = lane & 15, quad = lane >> 4;
    int r0 = t >> 2, q0 = (t & 3) * 8;
    int bp = (t >> 4) & 15;
    int boq8 = t & 15;
    int hi = w >> 2;
    int cb = boq8 * 8 + hi * 4;
    int pw = bp ^ ((boq8 & 3) << 2);
    const __hip_bfloat16* aR = srcA + (size_t)r0 * GG + q0;
    const __hip_bfloat16* aS = srcA + (size_t)(r0 + 128) * GG + q0;
    const float* wb0 = srcB + (size_t)(2 * bp) * OO + cb;
    f32x4 acc[4][4] = {};

    uint4 axl, axh; float4 bxa, bxb;   // reg set X
    uint4 ayl, ayh; float4 bya, byb;   // reg set Y

#define LOADX(kk) { axl = *(const uint4*)&aR[kk]; axh = *(const uint4*)&aS[kk]; \
                    const float* wn_ = wb0 + (size_t)(kk) * OO; \
                    bxa = *(const float4*)&wn_[0]; bxb = *(const float4*)&wn_[OO]; }
#define LOADY(kk) { ayl = *(const uint4*)&aR[kk]; ayh = *(const uint4*)&aS[kk]; \
                    const float* wn_ = wb0 + (size_t)(kk) * OO; \
                    bya = *(const float4*)&wn_[0]; byb = *(const float4*)&wn_[OO]; }
#define STOREX(buf) { *(uint4*)&lA[buf][t * 8] = axl; *(uint4*)&lA[buf][(t + 512) * 8] = axh; \
                      u32* d_ = &lB[buf][0]; \
                      d_[(cb + 0) * 16 + pw] = pack_bf2(bxa.x, bxb.x); \
                      d_[(cb + 1) * 16 + pw] = pack_bf2(bxa.y, bxb.y); \
                      d_[(cb + 2) * 16 + pw] = pack_bf2(bxa.z, bxb.z); \
                      d_[(cb + 3) * 16 + pw] = pack_bf2(bxa.w, bxb.w); }
#define STOREY(buf) { *(uint4*)&lA[buf][t * 8] = ayl; *(uint4*)&lA[buf][(t + 512) * 8] = ayh; \
                      u32* d_ = &lB[buf][0]; \
                      d_[(cb + 0) * 16 + pw] = pack_bf2(bya.x, byb.x); \
                      d_[(cb + 1) * 16 + pw] = pack_bf2(bya.y, byb.y); \
                      d_[(cb + 2) * 16 + pw] = pack_bf2(bya.z, byb.z); \
                      d_[(cb + 3) * 16 + pw] = pack_bf2(bya.w, byb.w); }
#define MMA(buf) { bf16x8 af[4]; \
    _Pragma("unroll") for (int fm = 0; fm < 4; ++fm) \
        af[fm] = *(const bf16x8*)&lA[buf][(mw + fm * 16 + lrow) * 32 + quad * 8]; \
    const u32* lbu = &lB[buf][0]; \
    _Pragma("unroll") for (int fn = 0; fn < 4; ++fn) { \
        int orow = ow + fn * 16 + lrow; \
        int fsw = ((orow >> 3) & 3) << 2; \
        bf16x8 bfr = *(const bf16x8*)&lbu[orow * 16 + (quad * 4 ^ fsw)]; \
        _Pragma("unroll") for (int fm = 0; fm < 4; ++fm) \
            acc[fm][fn] = __builtin_amdgcn_mfma_f32_16x16x32_bf16(af[fm], bfr, acc[fm][fn], 0, 0, 0); } }

    LOADX(0);        // tile 0
    LOADY(32);       // tile 1 (stays in flight across the prologue store)
    STOREX(0);       // tile 0 -> buf0 (compiler: counted vmcnt, leaves Y in flight)
    __syncthreads();
#pragma unroll 1
    for (int j = 0; j < 8; ++j) {
        int itE = 2 * j;
        // even iter: read buf0 (tile itE); Y holds tile itE+1; X free
        if (itE + 2 < 16) LOADX((itE + 2) * 32);
        MMA(0);
        STOREY(1);                       // tile itE+1 -> buf1
        __syncthreads();
        // odd iter: read buf1 (tile itE+1); X holds tile itE+2; Y free
        if (itE + 3 < 16) LOADY((itE + 3) * 32);
        MMA(1);
        if (itE + 2 < 16) STOREX(0);     // tile itE+2 -> buf0
        __syncthreads();
    }
#undef LOADX
#undef LOADY
#undef STOREX
#undef STOREY
#undef MMA
    // C/D layout: col=lane&15, row=quad*4+reg
#pragma unroll
    for (int fm = 0; fm < 4; ++fm) {
#pragma unroll
        for (int fn = 0; fn < 4; ++fn) {
            int col = o0 + ow + fn * 16 + lrow;
#pragma unroll
            for (int r = 0; r < 4; ++r) {
                int row = mw + fm * 16 + quad * 4 + r;
                part1[((size_t)s * NB + row) * NO + n * OO + col] = __float2bfloat16(acc[fm][fn][r]);
            }
        }
    }
}

// ---- combine 4 bf16 GEMM1 partials + bias -> h bf16 ----
__global__ __launch_bounds__(256) void combine1_k(const __hip_bfloat16* __restrict__ part1,
                                                  const float* __restrict__ bias,
                                                  __hip_bfloat16* __restrict__ h) {
    int j4 = blockIdx.x * 256 + threadIdx.x;
    int jj = j4 % (NO / 4);
    float4 a = ((const float4*)bias)[jj];
#pragma unroll
    for (int s = 0; s < 4; ++s) {
        ushort4 p = *(const ushort4*)&part1[(size_t)s * NB * NO + (size_t)j4 * 4];
        a.x += __bfloat162float(__ushort_as_bfloat16(p.x));
        a.y += __bfloat162float(__ushort_as_bfloat16(p.y));
        a.z += __bfloat162float(__ushort_as_bfloat16(p.z));
        a.w += __bfloat162float(__ushort_as_bfloat16(p.w));
    }
    ushort4 o;
    o.x = __bfloat16_as_ushort(__float2bfloat16(a.x));
    o.y = __bfloat16_as_ushort(__float2bfloat16(a.y));
    o.z = __bfloat16_as_ushort(__float2bfloat16(a.z));
    o.w = __bfloat16_as_ushort(__float2bfloat16(a.w));
    *(ushort4*)&h[(size_t)j4 * 4] = o;
}

// ---- GEMM2 split-K=41, double-buffered, unchanged ----
__global__ __launch_bounds__(256) void gemm2_k(const __hip_bfloat16* __restrict__ h,
                                               const __hip_bfloat16* __restrict__ W3t,
                                               float* __restrict__ part) {
    int bid0 = blockIdx.x;
    int bid = (bid0 & 7) * 82 + (bid0 >> 3);
    int e0 = (bid & 7) * 64;
    int m0 = ((bid >> 3) & 1) * 128;
    int s = bid >> 4;
    const __hip_bfloat16* srcA = h + (size_t)m0 * NO + s * 256;
    const __hip_bfloat16* srcB = W3t + (size_t)e0 * NO + s * 256;
    __shared__ __align__(16) __hip_bfloat16 lA[2][128 * 32];
    __shared__ __align__(16) __hip_bfloat16 lB[2][64 * 32];
    int t = threadIdx.x;
    int lane = t & 63, w = t >> 6;
    int mw = (w >> 1) * 64, ew = (w & 1) * 32;
    int lrow = lane & 15, quad = lane >> 4;
    int rA = t >> 2, qA = (t & 3) * 8;
    int rB = t >> 2, qB = (t & 3) * 8;
    f32x4 acc[4][2] = {};

    gl_lds16(srcA + (size_t)rA * NO + qA, &lA[0][t * 8]);
    gl_lds16(srcA + (size_t)(rA + 64) * NO + qA, &lA[0][(t + 256) * 8]);
    gl_lds16(srcB + (size_t)(rB & 63) * NO + qB, &lB[0][t * 8]);
    __syncthreads();
#pragma unroll 1
    for (int it = 0; it < 8; ++it) {
        int cur = it & 1;
        if (it + 1 < 8) {
            int k1 = (it + 1) * 32;
            gl_lds16(srcA + (size_t)rA * NO + k1 + qA, &lA[1 - cur][t * 8]);
            gl_lds16(srcA + (size_t)(rA + 64) * NO + k1 + qA, &lA[1 - cur][(t + 256) * 8]);
            gl_lds16(srcB + (size_t)(rB & 63) * NO + k1 + qB, &lB[1 - cur][t * 8]);
        }
        bf16x8 af[4];
#pragma unroll
        for (int fm = 0; fm < 4; ++fm)
            af[fm] = *(const bf16x8*)&lA[cur][(mw + fm * 16 + lrow) * 32 + quad * 8];
#pragma unroll
        for (int fn = 0; fn < 2; ++fn) {
            bf16x8 bfr = *(const bf16x8*)&lB[cur][(ew + fn * 16 + lrow) * 32 + quad * 8];
#pragma unroll
            for (int fm = 0; fm < 4; ++fm)
                acc[fm][fn] = __builtin_amdgcn_mfma_f32_16x16x32_bf16(af[fm], bfr, acc[fm][fn], 0, 0, 0);
        }
        __syncthreads();
    }
#pragma unroll
    for (int fm = 0; fm < 4; ++fm) {
#pragma unroll
        for (int fn = 0; fn < 2; ++fn) {
            int e = e0 + ew + fn * 16 + lrow;
#pragma unroll
            for (int r = 0; r < 4; ++r) {
                int row = m0 + mw + fm * 16 + quad * 4 + r;
                part[((size_t)s * NB + row) * EE + e] = acc[fm][fn][r];
            }
        }
    }
}

// ---- reduce partials + bias + leaky relu ----
__global__ __launch_bounds__(128) void reduce_k(const float* __restrict__ part,
                                                const float* __restrict__ b3,
                                                float* __restrict__ out) {
    int j = blockIdx.x * 128 + threadIdx.x;
    float4 a = make_float4(0.f, 0.f, 0.f, 0.f);
    for (int s = 0; s < NN; ++s) {
        float4 v = ((const float4*)part)[(size_t)s * (NB * EE / 4) + j];
        a.x += v.x; a.y += v.y; a.z += v.z; a.w += v.w;
    }
    float4 bv = ((const float4*)b3)[j & 127];
    a.x += bv.x; a.y += bv.y; a.z += bv.z; a.w += bv.w;
    a.x = a.x >= 0.f ? a.x : NEG_SLOPE * a.x;
    a.y = a.y >= 0.f ? a.y : NEG_SLOPE * a.y;
    a.z = a.z >= 0.f ? a.z : NEG_SLOPE * a.z;
    a.w = a.w >= 0.f ? a.w : NEG_SLOPE * a.w;
    ((float4*)out)[j] = a;
}

extern "C" void kernel_launch(void* const* d_in, const int* in_sizes, int n_in,
                              void* d_out, int out_size, void* d_ws, size_t ws_size,
                              hipStream_t stream) {
    const float* x = (const float*)d_in[0];
    const int* idx = (const int*)d_in[1];
    const float* W = (const float*)d_in[2];
    const float* bias = (const float*)d_in[3];
    const float* W3 = (const float*)d_in[4];
    const float* b3 = (const float*)d_in[5];
    float* out = (float*)d_out;

    char* ws = (char*)d_ws;
    const size_t g_off = 0;
    const size_t g_sz = (size_t)NN * NB * GG * 2;
    const size_t wt_off = g_off + g_sz;           // hosts part1 (4 planes bf16, 21.5 MB)
    const size_t wt_sz = (size_t)NN * GG * OO * 2;
    const size_t w3t_off = wt_off + wt_sz;
    const size_t w3t_sz = (size_t)NO * EE * 2;
    const size_t h_off = w3t_off + w3t_sz;
    const size_t h_sz = (size_t)NB * NO * 2;
    const size_t p_off = h_off + h_sz;            // gemm2 fp32 partials (21.5 MB)

    __hip_bfloat16* g = (__hip_bfloat16*)(ws + g_off);
    __hip_bfloat16* W3t = (__hip_bfloat16*)(ws + w3t_off);
    __hip_bfloat16* h = (__hip_bfloat16*)(ws + h_off);
    __hip_bfloat16* part1 = (__hip_bfloat16*)(ws + wt_off);
    float* part = (float*)(ws + p_off);

    // merged prep: gather + W3 transpose in one launch
    hipError_t aerr = hipFuncSetAttribute(reinterpret_cast<const void*>(prep_k),
                                          hipFuncAttributeMaxDynamicSharedMemorySize, 131072);
    if (aerr == hipSuccess) {
        prep_k<<<dim3(NB + NN * 8), 1024, 131072, stream>>>(x, idx, W3, g, W3t);
    } else {
        transpose_w3_k<<<dim3(NN * 8), 256, 0, stream>>>(W3, W3t);
        gather_half_k<<<dim3(512), 512, 0, stream>>>(x, idx, g);
    }
    // GEMM1: full-M 256x128 tile, split-K=4, 2-deep reg-staged pipeline
    gemm1_k<<<dim3(328), 512, 0, stream>>>(g, W, part1);
    // combine 4 partials + bias -> h bf16
    combine1_k<<<dim3(NB * NO / 4 / 256), 256, 0, stream>>>(part1, bias, h);
    // GEMM2 split-K, double-buffered
    gemm2_k<<<dim3(656), 256, 0, stream>>>(h, W3t, part);
    // reduce + bias + leaky relu
    reduce_k<<<dim3(256), 128, 0, stream>>>(part, b3, out);
}

// Round 9
// 258.050 us; speedup vs baseline: 1.0209x; 1.0209x over previous
//
#include <hip/hip_runtime.h>
#include <hip/hip_bf16.h>

#define NB 256
#define DD 65536
#define NN 41
#define GG 2048
#define OO 256
#define NO 10496
#define EE 512
#define NEG_SLOPE 0.2f

typedef __attribute__((ext_vector_type(8))) short bf16x8;
typedef __attribute__((ext_vector_type(4))) float f32x4;
typedef unsigned int u32;

// async global->LDS, 16B per lane (fallback paths only).
__device__ __forceinline__ void gl_lds16(const __hip_bfloat16* gsrc, __hip_bfloat16* lds) {
    __builtin_amdgcn_global_load_lds((const __attribute__((address_space(1))) u32*)gsrc,
                                     (__attribute__((address_space(3))) u32*)lds, 16, 0, 0);
}

__device__ __forceinline__ u32 pack_bf2(float lo, float hi) {
    u32 a = (u32)__bfloat16_as_ushort(__float2bfloat16(lo));
    u32 b = (u32)__bfloat16_as_ushort(__float2bfloat16(hi));
    return a | (b << 16);
}

// ---- fallback transpose for W3 (standalone) ----
__global__ __launch_bounds__(256) void transpose_w3_k(const float* __restrict__ W3,
                                                      __hip_bfloat16* __restrict__ W3t) {
    __shared__ u32 tb[64 * 128];
    int rem = blockIdx.x;
    int kc0 = (rem >> 3) * 256;
    int o0 = (rem & 7) * 64;
    int t = threadIdx.x;
    int p = t & 127;
    int oh = (t >> 7) * 32;
    const float* r0 = W3 + (size_t)(kc0 + 2 * p) * EE + o0 + oh;
    const float* r1 = r0 + EE;
#pragma unroll
    for (int c = 0; c < 8; ++c) {
        float4 a = *(const float4*)&r0[c * 4];
        float4 b = *(const float4*)&r1[c * 4];
        tb[(oh + c * 4 + 0) * 128 + p] = pack_bf2(a.x, b.x);
        tb[(oh + c * 4 + 1) * 128 + p] = pack_bf2(a.y, b.y);
        tb[(oh + c * 4 + 2) * 128 + p] = pack_bf2(a.z, b.z);
        tb[(oh + c * 4 + 3) * 128 + p] = pack_bf2(a.w, b.w);
    }
    __syncthreads();
    int w = t >> 6, l = t & 63;
    int lr = l >> 5;
    int ls = l & 31;
#pragma unroll
    for (int j = 0; j < 8; ++j) {
        int o = j * 8 + w * 2 + lr;
        uint4 v = *(const uint4*)&tb[o * 128 + ls * 4];
        *(uint4*)&W3t[(size_t)(o0 + o) * NO + kc0 + ls * 8] = v;
    }
}

// ---- merged prep: gather (blocks 0..255, 4x-unrolled MLP) + W3 transpose ----
__global__ __launch_bounds__(1024) void prep_k(const float* __restrict__ x,
                                               const int* __restrict__ idx,
                                               const float* __restrict__ W3,
                                               __hip_bfloat16* __restrict__ g,
                                               __hip_bfloat16* __restrict__ W3t) {
    extern __shared__ __hip_bfloat16 xr[];  // 131072 bytes
    int t = threadIdx.x;
    if (blockIdx.x < NB) {
        int b = blockIdx.x;
        const float4* xv = (const float4*)(x + (size_t)b * DD);
#pragma unroll
        for (int i = 0; i < 16; ++i) {
            float4 v = xv[t + 1024 * i];
            short4 p;
            p.x = (short)__bfloat16_as_ushort(__float2bfloat16(v.x));
            p.y = (short)__bfloat16_as_ushort(__float2bfloat16(v.y));
            p.z = (short)__bfloat16_as_ushort(__float2bfloat16(v.z));
            p.w = (short)__bfloat16_as_ushort(__float2bfloat16(v.w));
            *(short4*)&xr[(t + 1024 * i) * 4] = p;
        }
        __syncthreads();
        const int4* idx4 = (const int4*)idx;
        // 20992 int4 groups; batches of 4 (u, u+1024, u+2048, u+3072) -> 4x idx MLP,
        // 16 independent LDS reads in flight instead of 4.
#pragma unroll 1
        for (int i = 0; i < 5; ++i) {
            int u0 = t + i * 4096;
            int4 ia = idx4[u0];
            int4 ib = idx4[u0 + 1024];
            int4 ic = idx4[u0 + 2048];
            int4 id = idx4[u0 + 3072];
            ushort4 oa, ob, oc, od;
            oa.x = __bfloat16_as_ushort(xr[ia.x]); oa.y = __bfloat16_as_ushort(xr[ia.y]);
            oa.z = __bfloat16_as_ushort(xr[ia.z]); oa.w = __bfloat16_as_ushort(xr[ia.w]);
            ob.x = __bfloat16_as_ushort(xr[ib.x]); ob.y = __bfloat16_as_ushort(xr[ib.y]);
            ob.z = __bfloat16_as_ushort(xr[ib.z]); ob.w = __bfloat16_as_ushort(xr[ib.w]);
            oc.x = __bfloat16_as_ushort(xr[ic.x]); oc.y = __bfloat16_as_ushort(xr[ic.y]);
            oc.z = __bfloat16_as_ushort(xr[ic.z]); oc.w = __bfloat16_as_ushort(xr[ic.w]);
            od.x = __bfloat16_as_ushort(xr[id.x]); od.y = __bfloat16_as_ushort(xr[id.y]);
            od.z = __bfloat16_as_ushort(xr[id.z]); od.w = __bfloat16_as_ushort(xr[id.w]);
            int u;
            u = u0;        *(ushort4*)&g[((size_t)(u >> 9) * NB + b) * GG + (u & 511) * 4] = oa;
            u = u0 + 1024; *(ushort4*)&g[((size_t)(u >> 9) * NB + b) * GG + (u & 511) * 4] = ob;
            u = u0 + 2048; *(ushort4*)&g[((size_t)(u >> 9) * NB + b) * GG + (u & 511) * 4] = oc;
            u = u0 + 3072; *(ushort4*)&g[((size_t)(u >> 9) * NB + b) * GG + (u & 511) * 4] = od;
        }
        if (t < 512) {
            int u = t + 20480;
            int4 ii = idx4[u];
            ushort4 o;
            o.x = __bfloat16_as_ushort(xr[ii.x]); o.y = __bfloat16_as_ushort(xr[ii.y]);
            o.z = __bfloat16_as_ushort(xr[ii.z]); o.w = __bfloat16_as_ushort(xr[ii.w]);
            *(ushort4*)&g[((size_t)(u >> 9) * NB + b) * GG + (u & 511) * 4] = o;
        }
    } else {
        int c = blockIdx.x - NB;          // 0..327
        int kc0 = (c >> 3) * 256;
        int o0 = (c & 7) * 64;
        u32* tb = (u32*)xr;               // [64 o][128 kpair]
        int p = t & 127;
        int oh = (t >> 7) * 8;
        const float* r0 = W3 + (size_t)(kc0 + 2 * p) * EE + o0 + oh;
        const float* r1 = r0 + EE;
#pragma unroll
        for (int cc = 0; cc < 2; ++cc) {
            float4 a = *(const float4*)&r0[cc * 4];
            float4 b = *(const float4*)&r1[cc * 4];
            tb[(oh + cc * 4 + 0) * 128 + p] = pack_bf2(a.x, b.x);
            tb[(oh + cc * 4 + 1) * 128 + p] = pack_bf2(a.y, b.y);
            tb[(oh + cc * 4 + 2) * 128 + p] = pack_bf2(a.z, b.z);
            tb[(oh + cc * 4 + 3) * 128 + p] = pack_bf2(a.w, b.w);
        }
        __syncthreads();
        int o = t >> 4;
        int ls = t & 15;
        uint4 v0 = *(const uint4*)&tb[o * 128 + ls * 4];
        uint4 v1 = *(const uint4*)&tb[o * 128 + (ls + 16) * 4];
        __hip_bfloat16* drow = &W3t[(size_t)(o0 + o) * NO + kc0];
        *(uint4*)&drow[ls * 8] = v0;
        *(uint4*)&drow[(ls + 16) * 8] = v1;
    }
}

// ---- fallback gather (half row in 64 KiB static LDS) ----
__global__ __launch_bounds__(512) void gather_half_k(const float* __restrict__ x,
                                                     const int* __restrict__ idx,
                                                     __hip_bfloat16* __restrict__ g) {
    __shared__ __align__(16) __hip_bfloat16 xr[32768];
    int b = blockIdx.x >> 1;
    int h = blockIdx.x & 1;
    int t = threadIdx.x;
    const float4* xv = (const float4*)(x + (size_t)b * DD + h * 32768);
#pragma unroll
    for (int i = 0; i < 16; ++i) {
        float4 v = xv[t + 512 * i];
        short4 p;
        p.x = (short)__bfloat16_as_ushort(__float2bfloat16(v.x));
        p.y = (short)__bfloat16_as_ushort(__float2bfloat16(v.y));
        p.z = (short)__bfloat16_as_ushort(__float2bfloat16(v.z));
        p.w = (short)__bfloat16_as_ushort(__float2bfloat16(v.w));
        *(short4*)&xr[(t + 512 * i) * 4] = p;
    }
    __syncthreads();
    const int4* idx4 = (const int4*)idx;
    for (int u = t; u < NN * GG / 4; u += 512) {
        int4 ii = idx4[u];
        int n = u >> 9;
        int k = (u & 511) * 4;
        __hip_bfloat16* dst = &g[((size_t)n * NB + b) * GG + k];
        if ((ii.x >> 15) == h) dst[0] = xr[ii.x & 32767];
        if ((ii.y >> 15) == h) dst[1] = xr[ii.y & 32767];
        if ((ii.z >> 15) == h) dst[2] = xr[ii.z & 32767];
        if ((ii.w >> 15) == h) dst[3] = xr[ii.w & 32767];
    }
}

// ---- GEMM1: 128x128 tile (round-5 geometry: grid 656 = 41n*2m*2o*4s, 256 thr)
// + round-8 reg-staged 2-deep pipeline. High occupancy AND counted-vmcnt overlap
// (the untested quadrant). Fused W fp32 cast+transpose B-staging, verified math.
__global__ __launch_bounds__(256) void gemm1_k(const __hip_bfloat16* __restrict__ g,
                                               const float* __restrict__ W,
                                               __hip_bfloat16* __restrict__ part1) {
    int bid0 = blockIdx.x;
    int bid = (bid0 & 7) * 82 + (bid0 >> 3);
    int s = bid & 3;
    int o0 = ((bid >> 2) & 1) * 128;
    int m0 = ((bid >> 3) & 1) * 128;
    int n = bid >> 4;
    const __hip_bfloat16* srcA = g + ((size_t)n * NB + m0) * GG + s * 512;
    const float* srcB = W + ((size_t)n * GG + s * 512) * OO + o0;
    __shared__ __align__(16) __hip_bfloat16 lA[2][128 * 32];  // 16 KiB
    __shared__ __align__(16) u32 lB[2][128 * 16];             // 16 KiB
    int t = threadIdx.x;
    int lane = t & 63, w = t >> 6;
    int mw = (w >> 1) * 64, ow = (w & 1) * 64;
    int lrow = lane & 15, quad = lane >> 4;
    int r0 = t >> 2, q0 = (t & 3) * 8;              // A: rows r0, r0+64
    int bp = t >> 4;                                 // B: k-pair 0..15
    int boq = t & 15;                                // col octet
    int pw = bp ^ ((boq & 3) << 2);
    int cb = boq * 8;
    const __hip_bfloat16* aR = srcA + (size_t)r0 * GG + q0;
    const __hip_bfloat16* aS = srcA + (size_t)(r0 + 64) * GG + q0;
    const float* wb0 = srcB + (size_t)(2 * bp) * OO + cb;
    f32x4 acc[4][4] = {};

    uint4 axl, axh; float4 bxa, bxb, bxc, bxd;   // set X
    uint4 ayl, ayh; float4 bya, byb, byc, byd;   // set Y

#define LOADX(kk) { axl = *(const uint4*)&aR[kk]; axh = *(const uint4*)&aS[kk]; \
                    const float* wn_ = wb0 + (size_t)(kk) * OO; \
                    bxa = *(const float4*)&wn_[0];  bxc = *(const float4*)&wn_[4]; \
                    bxb = *(const float4*)&wn_[OO]; bxd = *(const float4*)&wn_[OO + 4]; }
#define LOADY(kk) { ayl = *(const uint4*)&aR[kk]; ayh = *(const uint4*)&aS[kk]; \
                    const float* wn_ = wb0 + (size_t)(kk) * OO; \
                    bya = *(const float4*)&wn_[0];  byc = *(const float4*)&wn_[4]; \
                    byb = *(const float4*)&wn_[OO]; byd = *(const float4*)&wn_[OO + 4]; }
#define STOREX(buf) { *(uint4*)&lA[buf][t * 8] = axl; *(uint4*)&lA[buf][(t + 256) * 8] = axh; \
                      u32* d_ = &lB[buf][0]; \
                      d_[(cb + 0) * 16 + pw] = pack_bf2(bxa.x, bxb.x); \
                      d_[(cb + 1) * 16 + pw] = pack_bf2(bxa.y, bxb.y); \
                      d_[(cb + 2) * 16 + pw] = pack_bf2(bxa.z, bxb.z); \
                      d_[(cb + 3) * 16 + pw] = pack_bf2(bxa.w, bxb.w); \
                      d_[(cb + 4) * 16 + pw] = pack_bf2(bxc.x, bxd.x); \
                      d_[(cb + 5) * 16 + pw] = pack_bf2(bxc.y, bxd.y); \
                      d_[(cb + 6) * 16 + pw] = pack_bf2(bxc.z, bxd.z); \
                      d_[(cb + 7) * 16 + pw] = pack_bf2(bxc.w, bxd.w); }
#define STOREY(buf) { *(uint4*)&lA[buf][t * 8] = ayl; *(uint4*)&lA[buf][(t + 256) * 8] = ayh; \
                      u32* d_ = &lB[buf][0]; \
                      d_[(cb + 0) * 16 + pw] = pack_bf2(bya.x, byb.x); \
                      d_[(cb + 1) * 16 + pw] = pack_bf2(bya.y, byb.y); \
                      d_[(cb + 2) * 16 + pw] = pack_bf2(bya.z, byb.z); \
                      d_[(cb + 3) * 16 + pw] = pack_bf2(bya.w, byb.w); \
                      d_[(cb + 4) * 16 + pw] = pack_bf2(byc.x, byd.x); \
                      d_[(cb + 5) * 16 + pw] = pack_bf2(byc.y, byd.y); \
                      d_[(cb + 6) * 16 + pw] = pack_bf2(byc.z, byd.z); \
                      d_[(cb + 7) * 16 + pw] = pack_bf2(byc.w, byd.w); }
#define MMA(buf) { bf16x8 af[4]; \
    _Pragma("unroll") for (int fm = 0; fm < 4; ++fm) \
        af[fm] = *(const bf16x8*)&lA[buf][(mw + fm * 16 + lrow) * 32 + quad * 8]; \
    const u32* lbu = &lB[buf][0]; \
    _Pragma("unroll") for (int fn = 0; fn < 4; ++fn) { \
        int orow = ow + fn * 16 + lrow; \
        int fsw = ((orow >> 3) & 3) << 2; \
        bf16x8 bfr = *(const bf16x8*)&lbu[orow * 16 + (quad * 4 ^ fsw)]; \
        _Pragma("unroll") for (int fm = 0; fm < 4; ++fm) \
            acc[fm][fn] = __builtin_amdgcn_mfma_f32_16x16x32_bf16(af[fm], bfr, acc[fm][fn], 0, 0, 0); } }

    LOADX(0);
    LOADY(32);
    STOREX(0);
    __syncthreads();
#pragma unroll 1
    for (int j = 0; j < 8; ++j) {
        int itE = 2 * j;
        if (itE + 2 < 16) LOADX((itE + 2) * 32);
        MMA(0);
        STOREY(1);
        __syncthreads();
        if (itE + 3 < 16) LOADY((itE + 3) * 32);
        MMA(1);
        if (itE + 2 < 16) STOREX(0);
        __syncthreads();
    }
#undef LOADX
#undef LOADY
#undef STOREX
#undef STOREY
#undef MMA
#pragma unroll
    for (int fm = 0; fm < 4; ++fm) {
#pragma unroll
        for (int fn = 0; fn < 4; ++fn) {
            int col = o0 + ow + fn * 16 + lrow;
#pragma unroll
            for (int r = 0; r < 4; ++r) {
                int row = m0 + mw + fm * 16 + quad * 4 + r;
                part1[((size_t)s * NB + row) * NO + n * OO + col] = __float2bfloat16(acc[fm][fn][r]);
            }
        }
    }
}

// ---- combine 4 bf16 GEMM1 partials + bias -> h bf16 ----
__global__ __launch_bounds__(256) void combine1_k(const __hip_bfloat16* __restrict__ part1,
                                                  const float* __restrict__ bias,
                                                  __hip_bfloat16* __restrict__ h) {
    int j4 = blockIdx.x * 256 + threadIdx.x;
    int jj = j4 % (NO / 4);
    float4 a = ((const float4*)bias)[jj];
#pragma unroll
    for (int s = 0; s < 4; ++s) {
        ushort4 p = *(const ushort4*)&part1[(size_t)s * NB * NO + (size_t)j4 * 4];
        a.x += __bfloat162float(__ushort_as_bfloat16(p.x));
        a.y += __bfloat162float(__ushort_as_bfloat16(p.y));
        a.z += __bfloat162float(__ushort_as_bfloat16(p.z));
        a.w += __bfloat162float(__ushort_as_bfloat16(p.w));
    }
    ushort4 o;
    o.x = __bfloat16_as_ushort(__float2bfloat16(a.x));
    o.y = __bfloat16_as_ushort(__float2bfloat16(a.y));
    o.z = __bfloat16_as_ushort(__float2bfloat16(a.z));
    o.w = __bfloat16_as_ushort(__float2bfloat16(a.w));
    *(ushort4*)&h[(size_t)j4 * 4] = o;
}

// ---- GEMM2: 128m x 128e tile, split-K=41, grid 328 = 41s*2m*4e, 256 thr,
// reg-staged 2-deep pipeline (same template as gemm1; B is a plain bf16 copy).
// e-split 4 halves A-traffic vs the old e-split 8. XCD swizzle 328 = 8*41.
__global__ __launch_bounds__(256) void gemm2_k(const __hip_bfloat16* __restrict__ h,
                                               const __hip_bfloat16* __restrict__ W3t,
                                               float* __restrict__ part) {
    int bid0 = blockIdx.x;
    int bid = (bid0 & 7) * 41 + (bid0 >> 3);
    int e0 = (bid & 3) * 128;
    int m0 = ((bid >> 2) & 1) * 128;
    int s = bid >> 3;  // 0..40
    const __hip_bfloat16* srcA = h + (size_t)m0 * NO + s * 256;
    const __hip_bfloat16* srcB = W3t + (size_t)e0 * NO + s * 256;
    __shared__ __align__(16) __hip_bfloat16 lA[2][128 * 32];  // 16 KiB
    __shared__ __align__(16) __hip_bfloat16 lB[2][128 * 32];  // 16 KiB
    int t = threadIdx.x;
    int lane = t & 63, w = t >> 6;
    int mw = (w >> 1) * 64, ew = (w & 1) * 64;
    int lrow = lane & 15, quad = lane >> 4;
    int r0 = t >> 2, q0 = (t & 3) * 8;
    const __hip_bfloat16* aR = srcA + (size_t)r0 * NO + q0;
    const __hip_bfloat16* aS = srcA + (size_t)(r0 + 64) * NO + q0;
    const __hip_bfloat16* bR = srcB + (size_t)r0 * NO + q0;
    const __hip_bfloat16* bS = srcB + (size_t)(r0 + 64) * NO + q0;
    f32x4 acc[4][4] = {};

    uint4 axl, axh, bxl, bxh;   // set X
    uint4 ayl, ayh, byl, byh;   // set Y

#define LOADX2(kk) { axl = *(const uint4*)&aR[kk]; axh = *(const uint4*)&aS[kk]; \
                     bxl = *(const uint4*)&bR[kk]; bxh = *(const uint4*)&bS[kk]; }
#define LOADY2(kk) { ayl = *(const uint4*)&aR[kk]; ayh = *(const uint4*)&aS[kk]; \
                     byl = *(const uint4*)&bR[kk]; byh = *(const uint4*)&bS[kk]; }
#define STOREX2(buf) { *(uint4*)&lA[buf][t * 8] = axl; *(uint4*)&lA[buf][(t + 256) * 8] = axh; \
                       *(uint4*)&lB[buf][t * 8] = bxl; *(uint4*)&lB[buf][(t + 256) * 8] = bxh; }
#define STOREY2(buf) { *(uint4*)&lA[buf][t * 8] = ayl; *(uint4*)&lA[buf][(t + 256) * 8] = ayh; \
                       *(uint4*)&lB[buf][t * 8] = byl; *(uint4*)&lB[buf][(t + 256) * 8] = byh; }
#define MMA2(buf) { bf16x8 af[4]; \
    _Pragma("unroll") for (int fm = 0; fm < 4; ++fm) \
        af[fm] = *(const bf16x8*)&lA[buf][(mw + fm * 16 + lrow) * 32 + quad * 8]; \
    _Pragma("unroll") for (int fn = 0; fn < 4; ++fn) { \
        bf16x8 bfr = *(const bf16x8*)&lB[buf][(ew + fn * 16 + lrow) * 32 + quad * 8]; \
        _Pragma("unroll") for (int fm = 0; fm < 4; ++fm) \
            acc[fm][fn] = __builtin_amdgcn_mfma_f32_16x16x32_bf16(af[fm], bfr, acc[fm][fn], 0, 0, 0); } }

    LOADX2(0);
    LOADY2(32);
    STOREX2(0);
    __syncthreads();
#pragma unroll 1
    for (int j = 0; j < 4; ++j) {
        int itE = 2 * j;
        if (itE + 2 < 8) LOADX2((itE + 2) * 32);
        MMA2(0);
        STOREY2(1);
        __syncthreads();
        if (itE + 3 < 8) LOADY2((itE + 3) * 32);
        MMA2(1);
        if (itE + 2 < 8) STOREX2(0);
        __syncthreads();
    }
#undef LOADX2
#undef LOADY2
#undef STOREX2
#undef STOREY2
#undef MMA2
#pragma unroll
    for (int fm = 0; fm < 4; ++fm) {
#pragma unroll
        for (int fn = 0; fn < 4; ++fn) {
            int e = e0 + ew + fn * 16 + lrow;
#pragma unroll
            for (int r = 0; r < 4; ++r) {
                int row = m0 + mw + fm * 16 + quad * 4 + r;
                part[((size_t)s * NB + row) * EE + e] = acc[fm][fn][r];
            }
        }
    }
}

// ---- reduce partials + bias + leaky relu ----
__global__ __launch_bounds__(128) void reduce_k(const float* __restrict__ part,
                                                const float* __restrict__ b3,
                                                float* __restrict__ out) {
    int j = blockIdx.x * 128 + threadIdx.x;
    float4 a = make_float4(0.f, 0.f, 0.f, 0.f);
    for (int s = 0; s < NN; ++s) {
        float4 v = ((const float4*)part)[(size_t)s * (NB * EE / 4) + j];
        a.x += v.x; a.y += v.y; a.z += v.z; a.w += v.w;
    }
    float4 bv = ((const float4*)b3)[j & 127];
    a.x += bv.x; a.y += bv.y; a.z += bv.z; a.w += bv.w;
    a.x = a.x >= 0.f ? a.x : NEG_SLOPE * a.x;
    a.y = a.y >= 0.f ? a.y : NEG_SLOPE * a.y;
    a.z = a.z >= 0.f ? a.z : NEG_SLOPE * a.z;
    a.w = a.w >= 0.f ? a.w : NEG_SLOPE * a.w;
    ((float4*)out)[j] = a;
}

extern "C" void kernel_launch(void* const* d_in, const int* in_sizes, int n_in,
                              void* d_out, int out_size, void* d_ws, size_t ws_size,
                              hipStream_t stream) {
    const float* x = (const float*)d_in[0];
    const int* idx = (const int*)d_in[1];
    const float* W = (const float*)d_in[2];
    const float* bias = (const float*)d_in[3];
    const float* W3 = (const float*)d_in[4];
    const float* b3 = (const float*)d_in[5];
    float* out = (float*)d_out;

    char* ws = (char*)d_ws;
    const size_t g_off = 0;
    const size_t g_sz = (size_t)NN * NB * GG * 2;
    const size_t wt_off = g_off + g_sz;           // hosts part1 (4 planes bf16, 21.5 MB)
    const size_t wt_sz = (size_t)NN * GG * OO * 2;
    const size_t w3t_off = wt_off + wt_sz;
    const size_t w3t_sz = (size_t)NO * EE * 2;
    const size_t h_off = w3t_off + w3t_sz;
    const size_t h_sz = (size_t)NB * NO * 2;
    const size_t p_off = h_off + h_sz;            // gemm2 fp32 partials (21.5 MB)

    __hip_bfloat16* g = (__hip_bfloat16*)(ws + g_off);
    __hip_bfloat16* W3t = (__hip_bfloat16*)(ws + w3t_off);
    __hip_bfloat16* h = (__hip_bfloat16*)(ws + h_off);
    __hip_bfloat16* part1 = (__hip_bfloat16*)(ws + wt_off);
    float* part = (float*)(ws + p_off);

    // merged prep: gather + W3 transpose in one launch
    hipError_t aerr = hipFuncSetAttribute(reinterpret_cast<const void*>(prep_k),
                                          hipFuncAttributeMaxDynamicSharedMemorySize, 131072);
    if (aerr == hipSuccess) {
        prep_k<<<dim3(NB + NN * 8), 1024, 131072, stream>>>(x, idx, W3, g, W3t);
    } else {
        transpose_w3_k<<<dim3(NN * 8), 256, 0, stream>>>(W3, W3t);
        gather_half_k<<<dim3(512), 512, 0, stream>>>(x, idx, g);
    }
    // GEMM1: 128x128, split-K 4, reg-staged 2-deep, high occupancy
    gemm1_k<<<dim3(656), 256, 0, stream>>>(g, W, part1);
    // combine 4 partials + bias -> h bf16
    combine1_k<<<dim3(NB * NO / 4 / 256), 256, 0, stream>>>(part1, bias, h);
    // GEMM2: 128x128, e-split 4, reg-staged 2-deep
    gemm2_k<<<dim3(328), 256, 0, stream>>>(h, W3t, part);
    // reduce + bias + leaky relu
    reduce_k<<<dim3(256), 128, 0, stream>>>(part, b3, out);
}